// Round 7
// baseline (616.880 us; speedup 1.0000x reference)
//
#include <hip/hip_runtime.h>
#include <hip/hip_bf16.h>

// ---------------------------------------------------------------------------
// lora_cross_attention, round 7: fp16 MFMA GEMM, race-fixed deep pipeline.
// conv(img,text,W* -> fp16) -> q = img x Wq^T -> k,v (fused, grid.z)
// -> fused attention (fp16, O in-place over q) -> out = O x Wo^T (fp32).
// GEMM: 256x256 tile, BK=32, 8 waves (2x4, each 128x64), QUAD-buffered
// 128 KB LDS, stage distance 3 K-tiles. Per K-tile (ONE barrier):
//   [buf certified by PREV iter's vmcnt(8)+barrier]
//   12 ds_read_b128 | stage tile t+3 (4 gload_lds) | lgkm(4) | 16 MFMA |
//   lgkm(0) | 16 MFMA | vmcnt(8) | s_barrier.
// vmcnt gate is globalized by the barrier BEFORE any wave reads the buffer
// (round-6 bug: reads issued pre-barrier against per-wave vmcnt only).
// ---------------------------------------------------------------------------

typedef unsigned short u16;
typedef _Float16 f16x8 __attribute__((ext_vector_type(8)));
typedef __attribute__((ext_vector_type(8))) short s16x8;
typedef __attribute__((ext_vector_type(4))) float f32x4;
typedef __attribute__((ext_vector_type(4))) short s16x4;

#define MFMAH(a, b, c) __builtin_amdgcn_mfma_f32_16x16x32_f16(a, b, c, 0, 0, 0)

__device__ __forceinline__ u16 f2h(float x) {
    _Float16 h = (_Float16)x;              // v_cvt_f16_f32, RNE
    return __builtin_bit_cast(u16, h);
}

__device__ __forceinline__ void gload16(const u16* g, const u16* l) {
    __builtin_amdgcn_global_load_lds(
        (const __attribute__((address_space(1))) unsigned int*)g,
        (__attribute__((address_space(3))) unsigned int*)l, 16, 0, 0);
}

// row-hash for the 16B-chunk swizzle (2-way max on ds_read_b128 = free)
__device__ __forceinline__ int rh(int r) { return (r & 3) ^ ((r >> 2) & 3); }

// ---------------------------------------------------------------------------
// fp32 -> fp16 conversion
// ---------------------------------------------------------------------------
__global__ void conv_h(const float* __restrict__ x, u16* __restrict__ h, int n8) {
    const int i = blockIdx.x * 256 + threadIdx.x;
    if (i >= n8) return;
    const f32x4 a = ((const f32x4*)x)[2 * i];
    const f32x4 b = ((const f32x4*)x)[2 * i + 1];
    u16 o[8];
#pragma unroll
    for (int j = 0; j < 4; ++j) { o[j] = f2h(a[j]); o[4 + j] = f2h(b[j]); }
    *(s16x8*)&h[(size_t)i << 3] = *(s16x8*)o;
}

struct Conv5Args {
    const float* x[5];
    u16* h[5];
    int n8[5];
};

__global__ void conv_h5(Conv5Args A) {
    const int z = blockIdx.y;
    const int i = blockIdx.x * 256 + threadIdx.x;
    if (i >= A.n8[z]) return;
    const float* x = A.x[z];
    const f32x4 a = ((const f32x4*)x)[2 * i];
    const f32x4 b = ((const f32x4*)x)[2 * i + 1];
    u16 o[8];
#pragma unroll
    for (int j = 0; j < 4; ++j) { o[j] = f2h(a[j]); o[4 + j] = f2h(b[j]); }
    *(s16x8*)&A.h[z][(size_t)i << 3] = *(s16x8*)o;
}

// ---------------------------------------------------------------------------
// C[M,N] = A[M,K] x B[N,K]^T + bias, fp16 in, fp32/fp16 out.
// 256x256 tile, BK=32, 512 threads (8 waves 2x4, each 128 rows x 64 cols).
// LDS: 4 buffers x 32 KB (buf i at u16 offset i*16384; A [256][32] @+0,
// B @+8192). Row r, 16B-slot s holds global k-chunk s ^ rh(r) (both sides).
// grid.z selects (B,bias,C) set 0/1 (fuses k and v projections).
// ---------------------------------------------------------------------------
template <int OUTF32>
__global__ __launch_bounds__(512, 2) void gemm_h_nt(
    const u16* __restrict__ A,
    const u16* __restrict__ B0, const float* __restrict__ bias0, void* __restrict__ C0,
    const u16* __restrict__ B1, const float* __restrict__ bias1, void* __restrict__ C1,
    int M, int N, int K, int nby) {
    __shared__ u16 lds[65536];   // 128 KB = 4 x 32 KB buffers

    const u16* B = B0; const float* bias = bias0; void* Cout = C0;
    if (blockIdx.z) { B = B1; bias = bias1; Cout = C1; }

    // XCD-bijective block swizzle (m204)
    const int nwg = gridDim.x;
    const int q8 = nwg >> 3, r8 = nwg & 7;
    const int xcd = blockIdx.x & 7, loc = blockIdx.x >> 3;
    const int wgid = (xcd < r8 ? xcd * (q8 + 1) : r8 * (q8 + 1) + (xcd - r8) * q8) + loc;
    const int bx = wgid / nby, by = wgid - bx * nby;
    const int row0 = bx * 256, col0 = by * 256;

    const int t = threadIdx.x, lane = t & 63, w = t >> 6;
    const int wr = w >> 2, wc = w & 3;
    const int l15 = lane & 15, lhi = lane >> 4;

    // staging: per tile, A = 1024 16B-chunks (256 rows x 4 slots), B same.
    // Thread t owns chunks t and 512+t of each. Global k-chunk = slot^rh(row).
    const u16* gpA[2]; const u16* gpB[2];
    int lofA[2], lofB[2];
#pragma unroll
    for (int it = 0; it < 2; ++it) {
        const int ci = it * 512 + t;
        const int row = ci >> 2, slot = ci & 3;
        const int gs = slot ^ rh(row);
        int ar = row0 + row; if (ar > M - 1) ar = M - 1;   // tail clamp (stores guarded)
        gpA[it] = A + (size_t)ar * K + (gs << 3);
        gpB[it] = B + (size_t)(col0 + row) * K + (gs << 3);
        lofA[it] = ci * 8;
        lofB[it] = 8192 + ci * 8;
    }

    // fragment read offsets: frag row base is a multiple of 16, so
    // rh(frag_row) = rh(l15) for every fragment.
    const int ss = rh(l15);
    int aof[8], bof[4];
#pragma unroll
    for (int i = 0; i < 8; ++i) {
        const int ar = wr * 128 + i * 16 + l15;
        aof[i] = ar * 32 + ((lhi ^ ss) << 3);
    }
#pragma unroll
    for (int n = 0; n < 4; ++n) {
        const int br = wc * 64 + n * 16 + l15;
        bof[n] = 8192 + br * 32 + ((lhi ^ ss) << 3);
    }

    f32x4 acc[8][4] = {};
    const int NT = K >> 5;   // K=1536 -> 48 (>= 4 required)

#define SBAR0() __builtin_amdgcn_sched_barrier(0)

    // prologue: stage tiles 0,1,2 into bufs 0,1,2 (12 loads, in order)
#pragma unroll
    for (int p = 0; p < 3; ++p) {
        const size_t kp = (size_t)p << 5;
        u16* lb = lds + (p << 14);
        gload16(gpA[0] + kp, lb + lofA[0]); gload16(gpA[1] + kp, lb + lofA[1]);
        gload16(gpB[0] + kp, lb + lofB[0]); gload16(gpB[1] + kp, lb + lofB[1]);
    }
    // certify tile 0 for ALL waves: own vmcnt then barrier
    asm volatile("s_waitcnt vmcnt(8)" ::: "memory");
    SBAR0(); __builtin_amdgcn_s_barrier(); SBAR0();

    for (int tt = 0; tt < NT; ++tt) {
        const int cb = (tt & 3) << 14;             // current buf (certified)
        u16* lsb = lds + (((tt + 3) & 3) << 14);   // stage target buf
        const int tx = (tt + 3 < NT) ? tt + 3 : tt + 3 - NT;  // wrap: vmcnt uniform
        const size_t kn = (size_t)tx << 5;

        f16x8 a0[4], a1[4], bb[4];

        // group 1: 8 ds_reads (B frags + A rows 0-63) — gated by lgkm(4)
#pragma unroll
        for (int nf = 0; nf < 4; ++nf) bb[nf] = *(const f16x8*)&lds[cb + bof[nf]];
#pragma unroll
        for (int mf = 0; mf < 4; ++mf) a0[mf] = *(const f16x8*)&lds[cb + aof[mf]];
        SBAR0();
        // group 2: 4 ds_reads (A rows 64-127) + stage tile t+3 (4 gloads)
#pragma unroll
        for (int mf = 0; mf < 4; ++mf) a1[mf] = *(const f16x8*)&lds[cb + aof[4 + mf]];
        gload16(gpA[0] + kn, lsb + lofA[0]);
        gload16(gpA[1] + kn, lsb + lofA[1]);
        gload16(gpB[0] + kn, lsb + lofB[0]);
        gload16(gpB[1] + kn, lsb + lofB[1]);

        // wait group 1 (4 ds_reads still outstanding), MFMA quadrant 0
        asm volatile("s_waitcnt lgkmcnt(4)" ::: "memory");
        SBAR0();
        __builtin_amdgcn_s_setprio(1);
#pragma unroll
        for (int nf = 0; nf < 4; ++nf)
#pragma unroll
            for (int mf = 0; mf < 4; ++mf)
                acc[mf][nf] = MFMAH(a0[mf], bb[nf], acc[mf][nf]);
        __builtin_amdgcn_s_setprio(0);
        // wait group 2, MFMA quadrant 1
        asm volatile("s_waitcnt lgkmcnt(0)" ::: "memory");
        SBAR0();
        __builtin_amdgcn_s_setprio(1);
#pragma unroll
        for (int nf = 0; nf < 4; ++nf)
#pragma unroll
            for (int mf = 0; mf < 4; ++mf)
                acc[4 + mf][nf] = MFMAH(a1[mf], bb[nf], acc[4 + mf][nf]);
        __builtin_amdgcn_s_setprio(0);

        // gate tile t+1 (own loads: 12 outstanding -> oldest 4 = tile t+1
        // retired), then barrier globalizes it + certifies buf reuse.
        asm volatile("s_waitcnt vmcnt(8)" ::: "memory");
        SBAR0(); __builtin_amdgcn_s_barrier(); SBAR0();
    }
    asm volatile("s_waitcnt vmcnt(0)" ::: "memory");

    // epilogue: +bias, store (C/D: col=lane&15, row=lhi*4+reg)
#pragma unroll
    for (int nf = 0; nf < 4; ++nf) {
        const int col = col0 + wc * 64 + nf * 16 + l15;
        const float bs = bias[col];
#pragma unroll
        for (int mf = 0; mf < 8; ++mf) {
            const int row = row0 + wr * 128 + mf * 16 + (lhi << 2);
#pragma unroll
            for (int r = 0; r < 4; ++r) {
                if (row + r < M) {
                    const float v = acc[mf][nf][r] + bs;
                    if (OUTF32) ((float*)Cout)[(size_t)(row + r) * N + col] = v;
                    else        ((u16*)Cout)[(size_t)(row + r) * N + col] = f2h(v);
                }
            }
        }
    }
#undef SBAR0
}

// ---------------------------------------------------------------------------
// Fused attention, fp16 in/out. One block per (qtile=64,h,b), 4 waves x 16
// q-rows. Sk=77 one-shot. O written IN-PLACE over q (each wave reads exactly
// the rows+head-slice it later writes; Q register-resident first).
// ---------------------------------------------------------------------------
#define ALDK 200
#define ALDP 104

__global__ void attn_fused(const u16* __restrict__ qbuf, const u16* __restrict__ kbuf,
                           const u16* __restrict__ vbuf, u16* __restrict__ obuf) {
    __shared__ u16 Ks[80 * ALDK];   // 32000 B
    __shared__ u16 Pls[64 * ALDP];  // 13312 B
    __shared__ u16 Vt[96 * ALDP];   // 19968 B (65280 total)

    const int t = threadIdx.x, lane = t & 63, w = t >> 6;
    const int qt = blockIdx.x, h = blockIdx.y, b = blockIdx.z;
    const int l15 = lane & 15, lhi = lane >> 4;

    // Q fragments straight from global fp16
    f16x8 qf[6];
    {
        const size_t qrow = (size_t)(b * 1024 + qt * 64 + w * 16 + l15);
        const u16* qp = qbuf + qrow * 1536 + h * 192 + (lhi << 3);
#pragma unroll
        for (int kt = 0; kt < 6; ++kt) qf[kt] = *(const f16x8*)(qp + kt * 32);
    }

    // stage K [80][192], rows >=77 zero
    for (int c = t; c < 80 * 24; c += 256) {
        const int s = c / 24, d8 = (c - s * 24) << 3;
        s16x8 val = {};
        if (s < 77) val = *(const s16x8*)&kbuf[(size_t)(b * 77 + s) * 1536 + h * 192 + d8];
        *(s16x8*)&Ks[s * ALDK + d8] = val;
    }
    // stage V^T half 0: d in [0,96); s fastest across lanes (conflict-free)
    for (int c = t; c < 96 * 12; c += 256) {
        const int s = c % 96, d8 = (c / 96) << 3;
        s16x8 val = {};
        if (s < 77) val = *(const s16x8*)&vbuf[(size_t)(b * 77 + s) * 1536 + h * 192 + d8];
#pragma unroll
        for (int j = 0; j < 8; ++j) Vt[(d8 + j) * ALDP + s] = (u16)val[j];
    }
    // zero P pad cols 80..95 (own rows)
    {
        const int row = w * 16 + l15;
        s16x4 z = {0, 0, 0, 0};
        *(s16x4*)&Pls[row * ALDP + 80 + (lhi << 2)] = z;
    }
    __syncthreads();

    // scores S[16 q-rows][80 k-cols] per wave
    f32x4 sacc[5] = {};
#pragma unroll
    for (int kt = 0; kt < 6; ++kt) {
#pragma unroll
        for (int nf = 0; nf < 5; ++nf) {
            f16x8 kf = *(const f16x8*)&Ks[(nf * 16 + l15) * ALDK + kt * 32 + (lhi << 3)];
            sacc[nf] = MFMAH(qf[kt], kf, sacc[nf]);
        }
    }

    // softmax per q-row (row = lhi*4 + r); P kept unnormalized
    float rps[4];
    const float scale = 0.07216878364870323f;   // 192^-0.5
#pragma unroll
    for (int r = 0; r < 4; ++r) {
        float m = -1e30f;
#pragma unroll
        for (int nf = 0; nf < 5; ++nf) {
            const int c = nf * 16 + l15;
            const float sv = sacc[nf][r] * scale;
            if (c < 77) m = fmaxf(m, sv);
        }
#pragma unroll
        for (int off = 1; off < 16; off <<= 1) m = fmaxf(m, __shfl_xor(m, off));
        float sum = 0.f;
#pragma unroll
        for (int nf = 0; nf < 5; ++nf) {
            const int c = nf * 16 + l15;
            const float p = (c < 77) ? __expf(sacc[nf][r] * scale - m) : 0.f;
            sacc[nf][r] = p;
            sum += p;
        }
#pragma unroll
        for (int off = 1; off < 16; off <<= 1) sum += __shfl_xor(sum, off);
        rps[r] = 1.0f / sum;   // sum >= 1
    }

    // write P (own 16 rows)
#pragma unroll
    for (int r = 0; r < 4; ++r)
#pragma unroll
        for (int nf = 0; nf < 5; ++nf)
            Pls[(w * 16 + (lhi << 2) + r) * ALDP + nf * 16 + l15] = f2h(sacc[nf][r]);
    __syncthreads();

    // P A-fragments
    f16x8 pa[3];
#pragma unroll
    for (int kt = 0; kt < 3; ++kt)
        pa[kt] = *(const f16x8*)&Pls[(w * 16 + l15) * ALDP + kt * 32 + (lhi << 3)];

    const size_t orow = (size_t)(b * 1024 + qt * 64 + w * 16 + (lhi << 2));

    // PV half 0 -> O[:, 0:96)
    {
        f32x4 oacc[6] = {};
#pragma unroll
        for (int kt = 0; kt < 3; ++kt)
#pragma unroll
            for (int nf = 0; nf < 6; ++nf) {
                f16x8 vf = *(const f16x8*)&Vt[(nf * 16 + l15) * ALDP + kt * 32 + (lhi << 3)];
                oacc[nf] = MFMAH(pa[kt], vf, oacc[nf]);
            }
#pragma unroll
        for (int nf = 0; nf < 6; ++nf) {
            const int col = h * 192 + nf * 16 + l15;
#pragma unroll
            for (int r = 0; r < 4; ++r)
                obuf[(orow + r) * 1536 + col] = f2h(oacc[nf][r] * rps[r]);
        }
    }
    __syncthreads();
    // stage V^T half 1: d in [96,192)
    for (int c = t; c < 96 * 12; c += 256) {
        const int s = c % 96, d8 = (c / 96) << 3;
        s16x8 val = {};
        if (s < 77) val = *(const s16x8*)&vbuf[(size_t)(b * 77 + s) * 1536 + h * 192 + 96 + d8];
#pragma unroll
        for (int j = 0; j < 8; ++j) Vt[(d8 + j) * ALDP + s] = (u16)val[j];
    }
    __syncthreads();
    // PV half 1 -> O[:, 96:192)
    {
        f32x4 oacc[6] = {};
#pragma unroll
        for (int kt = 0; kt < 3; ++kt)
#pragma unroll
            for (int nf = 0; nf < 6; ++nf) {
                f16x8 vf = *(const f16x8*)&Vt[(nf * 16 + l15) * ALDP + kt * 32 + (lhi << 3)];
                oacc[nf] = MFMAH(pa[kt], vf, oacc[nf]);
            }
#pragma unroll
        for (int nf = 0; nf < 6; ++nf) {
            const int col = h * 192 + 96 + nf * 16 + l15;
#pragma unroll
            for (int r = 0; r < 4; ++r)
                obuf[(orow + r) * 1536 + col] = f2h(oacc[nf][r] * rps[r]);
        }
    }
}

// ---------------------------------------------------------------------------
extern "C" void kernel_launch(void* const* d_in, const int* in_sizes, int n_in,
                              void* d_out, int out_size, void* d_ws, size_t ws_size,
                              hipStream_t stream) {
    const float* img  = (const float*)d_in[0];
    const float* text = (const float*)d_in[1];
    const float* Wq   = (const float*)d_in[2];
    const float* bq   = (const float*)d_in[3];
    const float* Wk   = (const float*)d_in[4];
    const float* bk   = (const float*)d_in[5];
    const float* Wv   = (const float*)d_in[6];
    const float* bv   = (const float*)d_in[7];
    const float* Wo   = (const float*)d_in[8];
    const float* bo   = (const float*)d_in[9];

    const size_t imgN = (size_t)32768 * 1536;
    const size_t txtN = (size_t)2464 * 1536;
    const size_t wN   = (size_t)1536 * 1536;

    // ws layout (~230 MB of fp16)
    u16* img_h = (u16*)d_ws;        // [imgN]
    u16* qb    = img_h + imgN;      // [imgN]  q fp16, O overwrites in-place
    u16* txt_h = qb + imgN;         // [txtN]
    u16* Wq_h  = txt_h + txtN;
    u16* Wk_h  = Wq_h + wN;
    u16* Wv_h  = Wk_h + wN;
    u16* Wo_h  = Wv_h + wN;
    u16* kb    = Wo_h + wN;         // [txtN]
    u16* vb    = kb + txtN;         // [txtN]

    // 1) conversions
    hipLaunchKernelGGL(conv_h, dim3((unsigned)(imgN / 8 / 256)), dim3(256),
                       0, stream, img, img_h, (int)(imgN / 8));
    Conv5Args ca;
    ca.x[0] = text; ca.h[0] = txt_h; ca.n8[0] = (int)(txtN / 8);
    ca.x[1] = Wq;   ca.h[1] = Wq_h;  ca.n8[1] = (int)(wN / 8);
    ca.x[2] = Wk;   ca.h[2] = Wk_h;  ca.n8[2] = (int)(wN / 8);
    ca.x[3] = Wv;   ca.h[3] = Wv_h;  ca.n8[3] = (int)(wN / 8);
    ca.x[4] = Wo;   ca.h[4] = Wo_h;  ca.n8[4] = (int)(wN / 8);
    hipLaunchKernelGGL(conv_h5, dim3((unsigned)((txtN / 8 + 255) / 256), 5),
                       dim3(256), 0, stream, ca);

    // 2) q projection (fp16 out): 128 x 6 tiles of 256x256
    hipLaunchKernelGGL((gemm_h_nt<0>), dim3(768), dim3(512), 0, stream,
                       img_h, Wq_h, bq, (void*)qb, Wq_h, bq, (void*)qb,
                       32768, 1536, 1536, 6);
    // 3) k,v projections fused via grid.z (fp16 out): 10 x 6 tiles
    hipLaunchKernelGGL((gemm_h_nt<0>), dim3(60, 1, 2), dim3(512), 0, stream,
                       txt_h, Wk_h, bk, (void*)kb, Wv_h, bv, (void*)vb,
                       2464, 1536, 1536, 6);
    // 4) attention (O in-place over q)
    hipLaunchKernelGGL(attn_fused, dim3(16, 8, 32), dim3(256), 0, stream,
                       qb, kb, vb, qb);
    // 5) output projection (fp32 out)
    hipLaunchKernelGGL((gemm_h_nt<1>), dim3(768), dim3(512), 0, stream,
                       qb, Wo_h, bo, d_out, Wo_h, bo, d_out,
                       32768, 1536, 1536, 6);
}